// Round 1
// baseline (162.118 us; speedup 1.0000x reference)
//
#include <hip/hip_runtime.h>

// SpikeEncoder: out[b,h] = ( sum_k count[b,k]*W2[h,k] + S*T*b2[h] ) / B
// where count[b,k] = #firings of LIF neuron (b,k) over S*T steps driven by
// x_s = h1[s,b,k],  h1 = emb[idx] @ W1^T + b1.
//
// ws layout: [0,16MB) h1 ; [16MB,16.25MB) count ; partials alias h1 (dead).

#define TSTEPS 10
#define SEQ    64
#define BATCH  64
#define EDIM   1024
#define HDIM   1024
#define NROW   (SEQ * BATCH)   // 4096
#define KSPLIT 16

// ---------------- GEMM1: h1[r,h] = sum_e emb[idx[r],e] * W1[h,e] + b1[h] ---
__global__ __launch_bounds__(256) void gemm1_gather(
    const int* __restrict__ idx,
    const float* __restrict__ emb,
    const float* __restrict__ W1,
    const float* __restrict__ bias1,
    float* __restrict__ h1)
{
    __shared__ float As[32][132];   // transposed A tile, pitch 132 (16B-aligned rows)
    __shared__ float Bs[32][132];
    __shared__ int rowidx[128];

    const int tid  = threadIdx.x;
    const int row0 = blockIdx.y * 128;
    const int col0 = blockIdx.x * 128;

    if (tid < 128) rowidx[tid] = idx[row0 + tid];
    __syncthreads();

    const int lr = tid >> 3;          // 0..31  row within staging pass
    const int lc = (tid & 7) * 4;     // 0..28  k offset (float4)

    const float* aptr[4];
    const float* bptr[4];
#pragma unroll
    for (int p = 0; p < 4; ++p) {
        aptr[p] = emb + (size_t)rowidx[p * 32 + lr] * EDIM + lc;
        bptr[p] = W1  + (size_t)(col0 + p * 32 + lr) * EDIM + lc;
    }

    const int tm = (tid >> 4) * 4;    // 0..60
    const int tn = (tid & 15) * 4;    // 0..60

    float acc[8][8];
#pragma unroll
    for (int i = 0; i < 8; ++i)
#pragma unroll
        for (int j = 0; j < 8; ++j) acc[i][j] = 0.f;

    float4 pa[4], pb[4];
#pragma unroll
    for (int p = 0; p < 4; ++p) {
        pa[p] = *(const float4*)(aptr[p]);
        pb[p] = *(const float4*)(bptr[p]);
    }

    for (int kt = 0; kt < 32; ++kt) {
        // commit staged registers to LDS (transposed)
#pragma unroll
        for (int p = 0; p < 4; ++p) {
            int r = p * 32 + lr;
            As[lc + 0][r] = pa[p].x; As[lc + 1][r] = pa[p].y;
            As[lc + 2][r] = pa[p].z; As[lc + 3][r] = pa[p].w;
            Bs[lc + 0][r] = pb[p].x; Bs[lc + 1][r] = pb[p].y;
            Bs[lc + 2][r] = pb[p].z; Bs[lc + 3][r] = pb[p].w;
        }
        __syncthreads();

        // prefetch next k-tile into registers (hides HBM/L2 latency under FMAs)
        if (kt < 31) {
            const int k0 = (kt + 1) * 32;
#pragma unroll
            for (int p = 0; p < 4; ++p) {
                pa[p] = *(const float4*)(aptr[p] + k0);
                pb[p] = *(const float4*)(bptr[p] + k0);
            }
        }

#pragma unroll 8
        for (int k = 0; k < 32; ++k) {
            float4 a0  = *(const float4*)&As[k][tm];
            float4 a1  = *(const float4*)&As[k][tm + 64];
            float4 bb0 = *(const float4*)&Bs[k][tn];
            float4 bb1 = *(const float4*)&Bs[k][tn + 64];
            float av[8] = {a0.x, a0.y, a0.z, a0.w, a1.x, a1.y, a1.z, a1.w};
            float bv[8] = {bb0.x, bb0.y, bb0.z, bb0.w, bb1.x, bb1.y, bb1.z, bb1.w};
#pragma unroll
            for (int i = 0; i < 8; ++i)
#pragma unroll
                for (int j = 0; j < 8; ++j)
                    acc[i][j] += av[i] * bv[j];
        }
        __syncthreads();
    }

    // epilogue: + bias, store
    float4 c0 = *(const float4*)(bias1 + col0 + tn);
    float4 c1 = *(const float4*)(bias1 + col0 + tn + 64);
    float bbv[8] = {c0.x, c0.y, c0.z, c0.w, c1.x, c1.y, c1.z, c1.w};
#pragma unroll
    for (int i = 0; i < 8; ++i) {
        const int r = row0 + tm + (i < 4 ? i : 64 + (i - 4));
        float* orow = h1 + (size_t)r * HDIM + col0;
        float4 o0, o1;
        o0.x = acc[i][0] + bbv[0]; o0.y = acc[i][1] + bbv[1];
        o0.z = acc[i][2] + bbv[2]; o0.w = acc[i][3] + bbv[3];
        o1.x = acc[i][4] + bbv[4]; o1.y = acc[i][5] + bbv[5];
        o1.z = acc[i][6] + bbv[6]; o1.w = acc[i][7] + bbv[7];
        *(float4*)(orow + tn)      = o0;
        *(float4*)(orow + tn + 64) = o1;
    }
}

// ---------------- LIF spike-count: pure elementwise recurrence ------------
__global__ __launch_bounds__(256) void lif_count(
    const float* __restrict__ h1,
    const float* __restrict__ pthr,
    const float* __restrict__ pleak,
    float* __restrict__ cnt)
{
    const int i = blockIdx.x * 256 + threadIdx.x;   // = b*HDIM + k
    const float thr = pthr[0];
    const float lk  = pleak[0];
    float mem1 = 0.f, c = 0.f;
    for (int s = 0; s < SEQ; ++s) {
        const float x = h1[(size_t)s * (BATCH * HDIM) + i];
#pragma unroll
        for (int t = 0; t < TSTEPS; ++t) {
            mem1 = lk * mem1 + x;
            // thr==1.0: mem1/thr - 1 > 0  <=>  mem1 > thr (exact)
            if (mem1 > thr) { c += 1.f; mem1 -= thr; }
        }
    }
    cnt[i] = c;
}

// ---------------- GEMM2 (K-split partials): part[kc][b][h] ----------------
__global__ __launch_bounds__(256) void gemm2_partial(
    const float* __restrict__ cnt,   // [64][1024]
    const float* __restrict__ W2,    // [1024][1024], out[b,h] += cnt[b,k]*W2[h,k]
    float* __restrict__ part)        // [KSPLIT][64][1024]
{
    __shared__ float As[32][68];
    __shared__ float Bs[32][132];

    const int tid   = threadIdx.x;
    const int col0  = blockIdx.x * 128;
    const int kc    = blockIdx.y;          // 0..15
    const int kbase = kc * 64;

    const int lr = tid >> 3;
    const int lc = (tid & 7) * 4;
    const int tm = (tid >> 4) * 4;    // 0..60 (rows = b)
    const int tn = (tid & 15) * 4;

    float acc[4][8];
#pragma unroll
    for (int i = 0; i < 4; ++i)
#pragma unroll
        for (int j = 0; j < 8; ++j) acc[i][j] = 0.f;

    for (int kt = 0; kt < 2; ++kt) {
        const int k0 = kbase + kt * 32;
#pragma unroll
        for (int p = 0; p < 2; ++p) {
            int r = p * 32 + lr;
            float4 v = *(const float4*)(cnt + (size_t)r * HDIM + k0 + lc);
            As[lc + 0][r] = v.x; As[lc + 1][r] = v.y;
            As[lc + 2][r] = v.z; As[lc + 3][r] = v.w;
        }
#pragma unroll
        for (int p = 0; p < 4; ++p) {
            int r = p * 32 + lr;
            float4 v = *(const float4*)(W2 + (size_t)(col0 + r) * HDIM + k0 + lc);
            Bs[lc + 0][r] = v.x; Bs[lc + 1][r] = v.y;
            Bs[lc + 2][r] = v.z; Bs[lc + 3][r] = v.w;
        }
        __syncthreads();
#pragma unroll 8
        for (int k = 0; k < 32; ++k) {
            float4 a   = *(const float4*)&As[k][tm];
            float4 bb0 = *(const float4*)&Bs[k][tn];
            float4 bb1 = *(const float4*)&Bs[k][tn + 64];
            float av[4] = {a.x, a.y, a.z, a.w};
            float bv[8] = {bb0.x, bb0.y, bb0.z, bb0.w, bb1.x, bb1.y, bb1.z, bb1.w};
#pragma unroll
            for (int i = 0; i < 4; ++i)
#pragma unroll
                for (int j = 0; j < 8; ++j)
                    acc[i][j] += av[i] * bv[j];
        }
        __syncthreads();
    }

#pragma unroll
    for (int i = 0; i < 4; ++i) {
        float* prow = part + (size_t)kc * (BATCH * HDIM) + (size_t)(tm + i) * HDIM + col0;
        float4 o0, o1;
        o0.x = acc[i][0]; o0.y = acc[i][1]; o0.z = acc[i][2]; o0.w = acc[i][3];
        o1.x = acc[i][4]; o1.y = acc[i][5]; o1.z = acc[i][6]; o1.w = acc[i][7];
        *(float4*)(prow + tn)      = o0;
        *(float4*)(prow + tn + 64) = o1;
    }
}

// ---------------- final reduce: out = (sum_kc part + 640*b2) / 64 ---------
__global__ __launch_bounds__(256) void reduce_out(
    const float* __restrict__ part,
    const float* __restrict__ b2,
    float* __restrict__ out)
{
    const int i = blockIdx.x * 256 + threadIdx.x;
    float s = 0.f;
#pragma unroll
    for (int kc = 0; kc < KSPLIT; ++kc)
        s += part[(size_t)kc * (BATCH * HDIM) + i];
    const int h = i & (HDIM - 1);
    out[i] = (s + (float)(SEQ * TSTEPS) * b2[h]) * (1.0f / (float)BATCH);
}

extern "C" void kernel_launch(void* const* d_in, const int* in_sizes, int n_in,
                              void* d_out, int out_size, void* d_ws, size_t ws_size,
                              hipStream_t stream)
{
    (void)in_sizes; (void)n_in; (void)out_size; (void)ws_size;

    const int*   idx  = (const int*)d_in[0];
    const float* emb  = (const float*)d_in[1];
    const float* W1   = (const float*)d_in[2];
    const float* b1   = (const float*)d_in[3];
    const float* W2   = (const float*)d_in[4];
    const float* b2   = (const float*)d_in[5];
    const float* thr  = (const float*)d_in[6];
    const float* leak = (const float*)d_in[7];
    float* out = (float*)d_out;

    float* h1   = (float*)d_ws;                                   // 16 MB
    float* cnt  = (float*)((char*)d_ws + (size_t)NROW * HDIM * 4); // 256 KB
    float* part = (float*)d_ws;  // aliases h1 — h1 is dead after lif_count

    dim3 g1(HDIM / 128, NROW / 128);   // (8, 32) = 256 blocks
    gemm1_gather<<<g1, 256, 0, stream>>>(idx, emb, W1, b1, h1);

    lif_count<<<dim3((BATCH * HDIM) / 256), 256, 0, stream>>>(h1, thr, leak, cnt);

    gemm2_partial<<<dim3(HDIM / 128, KSPLIT), 256, 0, stream>>>(cnt, W2, part);

    reduce_out<<<dim3((BATCH * HDIM) / 256), 256, 0, stream>>>(part, b2, out);
}

// Round 2
// 75.805 us; speedup vs baseline: 2.1386x; 2.1386x over previous
//
#include <hip/hip_runtime.h>

// SpikeEncoder: out[b,h] = ( sum_k count[b,k]*W2[h,k] + S*T*b2[h] ) / B
// GEMM1 done in split-bf16 MFMA: A*W ~= Ahi*Whi + Ahi*Wlo + Alo*Whi.
//
// ws layout: [0,16M) h1 (later aliased by part) ; [16M,16.25M) cnt ;
//            [16.25M) Ahi(8M) Alo(8M) Whi(2M) Wlo(2M).  Total ~36.3 MB.

#define TSTEPS 10
#define SEQ    64
#define BATCH  64
#define EDIM   1024
#define HDIM   1024
#define NROW   (SEQ * BATCH)   // 4096
#define KSPLIT 16

typedef unsigned short u16;
typedef __attribute__((ext_vector_type(8))) short  short8;
typedef __attribute__((ext_vector_type(8))) unsigned short ushort8;
typedef __attribute__((ext_vector_type(4))) float  f32x4;

__device__ __forceinline__ u16 rne_bf16(float x) {
    unsigned u = __float_as_uint(x);
    u += 0x7fffu + ((u >> 16) & 1u);
    return (u16)(u >> 16);
}
__device__ __forceinline__ float bf16f(u16 h) {
    return __uint_as_float(((unsigned)h) << 16);
}

__device__ __forceinline__ void gld16(const u16* g, u16* l) {
    __builtin_amdgcn_global_load_lds(
        (const __attribute__((address_space(1))) void*)g,
        (__attribute__((address_space(3))) void*)l, 16, 0, 0);
}

// ------------- split fp32 rows -> bf16 hi/lo (optional gather) -------------
__global__ __launch_bounds__(256) void split_rows(
    const float* __restrict__ src, const int* __restrict__ idx,
    u16* __restrict__ hi, u16* __restrict__ lo)
{
    const int t = blockIdx.x * 256 + threadIdx.x;
    const int r = t >> 7;                 // 128 threads per 1024-wide row
    const int c = (t & 127) << 3;
    const int srow = idx ? idx[r] : r;
    const float* p = src + (size_t)srow * EDIM + c;
    float4 v0 = *(const float4*)p;
    float4 v1 = *(const float4*)(p + 4);
    float x[8] = {v0.x, v0.y, v0.z, v0.w, v1.x, v1.y, v1.z, v1.w};
    ushort8 h, l;
#pragma unroll
    for (int j = 0; j < 8; ++j) {
        u16 hh = rne_bf16(x[j]);
        h[j] = hh;
        l[j] = rne_bf16(x[j] - bf16f(hh));
    }
    *(ushort8*)(hi + (size_t)r * EDIM + c) = h;
    *(ushort8*)(lo + (size_t)r * EDIM + c) = l;
}

// ------------- GEMM1 via MFMA: h1 = [Ahi|Alo] x [Whi|Wlo] + b1 -------------
#define BM 128
#define BN 64
#define BK 32
#define NT (EDIM / BK)        // 32 k-steps
#define AH_OFF 0              // 128*32 u16
#define AL_OFF 4096
#define WH_OFF 8192           // 64*32 u16
#define WL_OFF 10240
#define BUFE   12288          // u16 per buffer (24 KB)

__global__ __launch_bounds__(256) void gemm1_mfma(
    const u16* __restrict__ Ahi, const u16* __restrict__ Alo,
    const u16* __restrict__ Whi, const u16* __restrict__ Wlo,
    const float* __restrict__ bias1, float* __restrict__ h1)
{
    __shared__ u16 lds[2 * BUFE];

    // bijective XCD swizzle (512 % 8 == 0) + 8x8 2D chunks for L2 locality
    const int bid = blockIdx.x;
    const int wg  = (bid & 7) * 64 + (bid >> 3);
    const int ch  = wg >> 6;                       // 0..7
    const int by  = (ch >> 1) * 8 + ((wg & 63) >> 3);  // 0..31
    const int bx  = (ch & 1) * 8 + (wg & 7);           // 0..15
    const int row0 = by * BM, col0 = bx * BN;

    const int tid  = threadIdx.x;
    const int wave = tid >> 6, lane = tid & 63;
    const int wm = wave >> 1, wn = wave & 1;       // wave grid 2x2, tile 64x32
    const int lrow = lane & 15, kgrp = lane >> 4;

    // staging: per-lane source offset with inverse slot-swizzle
    const int sr = lane >> 2;                                  // 0..15
    const int kc = (((lane & 3) ^ ((lane >> 3) & 3)) << 3);    // swizzled k src
    const int ca = wave * 2;                                   // A chunk base
    const size_t a0 = (size_t)(row0 + ca * 16 + sr) * EDIM + kc;
    const size_t a1 = (size_t)(row0 + ca * 16 + 16 + sr) * EDIM + kc;
    const size_t w0 = (size_t)(col0 + wave * 16 + sr) * EDIM + kc;

    f32x4 acc[4][2];
    const f32x4 zero = {0.f, 0.f, 0.f, 0.f};
#pragma unroll
    for (int m = 0; m < 4; ++m)
#pragma unroll
        for (int n = 0; n < 2; ++n) acc[m][n] = zero;

    auto STAGE = [&](int k0, int b) {
        u16* lb = &lds[b * BUFE];
        gld16(Ahi + a0 + k0, lb + AH_OFF + ca * 512);
        gld16(Ahi + a1 + k0, lb + AH_OFF + (ca + 1) * 512);
        gld16(Alo + a0 + k0, lb + AL_OFF + ca * 512);
        gld16(Alo + a1 + k0, lb + AL_OFF + (ca + 1) * 512);
        gld16(Whi + w0 + k0, lb + WH_OFF + wave * 512);
        gld16(Wlo + w0 + k0, lb + WL_OFF + wave * 512);
    };

    auto COMPUTE = [&](int b) {
        const u16* lb = &lds[b * BUFE];
        short8 ah[4], al[4], bh[2], bl[2];
#pragma unroll
        for (int n = 0; n < 2; ++n) {
            const int col = wn * 32 + n * 16 + lrow;
            const int s = kgrp ^ ((col >> 1) & 3);
            const u16* p = lb + WH_OFF + col * 32 + s * 8;
            bh[n] = *(const short8*)p;
            bl[n] = *(const short8*)(p + (WL_OFF - WH_OFF));
        }
#pragma unroll
        for (int m = 0; m < 4; ++m) {
            const int row = wm * 64 + m * 16 + lrow;
            const int s = kgrp ^ ((row >> 1) & 3);
            const u16* p = lb + AH_OFF + row * 32 + s * 8;
            ah[m] = *(const short8*)p;
            al[m] = *(const short8*)(p + (AL_OFF - AH_OFF));
        }
#pragma unroll
        for (int m = 0; m < 4; ++m)
#pragma unroll
            for (int n = 0; n < 2; ++n) {
                acc[m][n] = __builtin_amdgcn_mfma_f32_16x16x32_bf16(ah[m], bh[n], acc[m][n], 0, 0, 0);
                acc[m][n] = __builtin_amdgcn_mfma_f32_16x16x32_bf16(ah[m], bl[n], acc[m][n], 0, 0, 0);
                acc[m][n] = __builtin_amdgcn_mfma_f32_16x16x32_bf16(al[m], bh[n], acc[m][n], 0, 0, 0);
            }
    };

    STAGE(0, 0);
    __syncthreads();
    int cur = 0;
#pragma unroll 2
    for (int kt = 0; kt < NT; ++kt) {
        if (kt + 1 < NT) STAGE((kt + 1) * BK, cur ^ 1);
        COMPUTE(cur);
        __syncthreads();
        cur ^= 1;
    }

    // epilogue: C/D layout col=lane&15, row=(lane>>4)*4+j
#pragma unroll
    for (int n = 0; n < 2; ++n) {
        const int col = col0 + wn * 32 + n * 16 + lrow;
        const float bv = bias1[col];
#pragma unroll
        for (int m = 0; m < 4; ++m) {
            const int rb = row0 + wm * 64 + m * 16 + kgrp * 4;
            float* o = h1 + (size_t)rb * HDIM + col;
#pragma unroll
            for (int j = 0; j < 4; ++j)
                o[(size_t)j * HDIM] = acc[m][n][j] + bv;
        }
    }
}

// ---------------- LIF spike-count: pure elementwise recurrence ------------
__global__ __launch_bounds__(256) void lif_count(
    const float* __restrict__ h1,
    const float* __restrict__ pthr,
    const float* __restrict__ pleak,
    float* __restrict__ cnt)
{
    const int i = blockIdx.x * 256 + threadIdx.x;
    const float thr = pthr[0];
    const float lk  = pleak[0];
    float mem1 = 0.f, c = 0.f;
    for (int s = 0; s < SEQ; ++s) {
        const float x = h1[(size_t)s * (BATCH * HDIM) + i];
#pragma unroll
        for (int t = 0; t < TSTEPS; ++t) {
            mem1 = lk * mem1 + x;
            if (mem1 > thr) { c += 1.f; mem1 -= thr; }
        }
    }
    cnt[i] = c;
}

// ---------------- GEMM2 (K-split partials): part[kc][b][h] ----------------
__global__ __launch_bounds__(256) void gemm2_partial(
    const float* __restrict__ cnt,
    const float* __restrict__ W2,
    float* __restrict__ part)
{
    __shared__ float As[32][68];
    __shared__ float Bs[32][132];

    const int tid   = threadIdx.x;
    const int col0  = blockIdx.x * 128;
    const int kc    = blockIdx.y;
    const int kbase = kc * 64;

    const int lr = tid >> 3;
    const int lc = (tid & 7) * 4;
    const int tm = (tid >> 4) * 4;
    const int tn = (tid & 15) * 4;

    float acc[4][8];
#pragma unroll
    for (int i = 0; i < 4; ++i)
#pragma unroll
        for (int j = 0; j < 8; ++j) acc[i][j] = 0.f;

    for (int kt = 0; kt < 2; ++kt) {
        const int k0 = kbase + kt * 32;
#pragma unroll
        for (int p = 0; p < 2; ++p) {
            int r = p * 32 + lr;
            float4 v = *(const float4*)(cnt + (size_t)r * HDIM + k0 + lc);
            As[lc + 0][r] = v.x; As[lc + 1][r] = v.y;
            As[lc + 2][r] = v.z; As[lc + 3][r] = v.w;
        }
#pragma unroll
        for (int p = 0; p < 4; ++p) {
            int r = p * 32 + lr;
            float4 v = *(const float4*)(W2 + (size_t)(col0 + r) * HDIM + k0 + lc);
            Bs[lc + 0][r] = v.x; Bs[lc + 1][r] = v.y;
            Bs[lc + 2][r] = v.z; Bs[lc + 3][r] = v.w;
        }
        __syncthreads();
#pragma unroll 8
        for (int k = 0; k < 32; ++k) {
            float4 a   = *(const float4*)&As[k][tm];
            float4 bb0 = *(const float4*)&Bs[k][tn];
            float4 bb1 = *(const float4*)&Bs[k][tn + 64];
            float av[4] = {a.x, a.y, a.z, a.w};
            float bv[8] = {bb0.x, bb0.y, bb0.z, bb0.w, bb1.x, bb1.y, bb1.z, bb1.w};
#pragma unroll
            for (int i = 0; i < 4; ++i)
#pragma unroll
                for (int j = 0; j < 8; ++j)
                    acc[i][j] += av[i] * bv[j];
        }
        __syncthreads();
    }

#pragma unroll
    for (int i = 0; i < 4; ++i) {
        float* prow = part + (size_t)kc * (BATCH * HDIM) + (size_t)(tm + i) * HDIM + col0;
        float4 o0, o1;
        o0.x = acc[i][0]; o0.y = acc[i][1]; o0.z = acc[i][2]; o0.w = acc[i][3];
        o1.x = acc[i][4]; o1.y = acc[i][5]; o1.z = acc[i][6]; o1.w = acc[i][7];
        *(float4*)(prow + tn)      = o0;
        *(float4*)(prow + tn + 64) = o1;
    }
}

// ---------------- final reduce: out = (sum_kc part + 640*b2) / 64 ---------
__global__ __launch_bounds__(256) void reduce_out(
    const float* __restrict__ part,
    const float* __restrict__ b2,
    float* __restrict__ out)
{
    const int i = blockIdx.x * 256 + threadIdx.x;
    float s = 0.f;
#pragma unroll
    for (int kc = 0; kc < KSPLIT; ++kc)
        s += part[(size_t)kc * (BATCH * HDIM) + i];
    const int h = i & (HDIM - 1);
    out[i] = (s + (float)(SEQ * TSTEPS) * b2[h]) * (1.0f / (float)BATCH);
}

extern "C" void kernel_launch(void* const* d_in, const int* in_sizes, int n_in,
                              void* d_out, int out_size, void* d_ws, size_t ws_size,
                              hipStream_t stream)
{
    (void)in_sizes; (void)n_in; (void)out_size; (void)ws_size;

    const int*   idx  = (const int*)d_in[0];
    const float* emb  = (const float*)d_in[1];
    const float* W1   = (const float*)d_in[2];
    const float* b1   = (const float*)d_in[3];
    const float* W2   = (const float*)d_in[4];
    const float* b2   = (const float*)d_in[5];
    const float* thr  = (const float*)d_in[6];
    const float* leak = (const float*)d_in[7];
    float* out = (float*)d_out;

    char* ws = (char*)d_ws;
    float* h1  = (float*)ws;                                  // 16 MB
    float* cnt = (float*)(ws + (size_t)NROW * HDIM * 4);      // 256 KB
    u16* ahi = (u16*)(ws + (size_t)NROW * HDIM * 4 + (size_t)BATCH * HDIM * 4);
    u16* alo = ahi + (size_t)NROW * EDIM;
    u16* whi = alo + (size_t)NROW * EDIM;
    u16* wlo = whi + (size_t)HDIM * EDIM;
    float* part = (float*)ws;   // aliases h1 (dead after lif_count)

    split_rows<<<dim3(NROW * 128 / 256), 256, 0, stream>>>(emb, idx, ahi, alo);
    split_rows<<<dim3(HDIM * 128 / 256), 256, 0, stream>>>(W1, nullptr, whi, wlo);

    gemm1_mfma<<<dim3((NROW / BM) * (HDIM / BN)), 256, 0, stream>>>(
        ahi, alo, whi, wlo, b1, h1);

    lif_count<<<dim3((BATCH * HDIM) / 256), 256, 0, stream>>>(h1, thr, leak, cnt);

    gemm2_partial<<<dim3(HDIM / 128, KSPLIT), 256, 0, stream>>>(cnt, W2, part);

    reduce_out<<<dim3((BATCH * HDIM) / 256), 256, 0, stream>>>(part, b2, out);
}

// Round 3
// 64.680 us; speedup vs baseline: 2.5065x; 1.1720x over previous
//
#include <hip/hip_runtime.h>

// SpikeEncoder: out[b,h] = ( sum_k count[b,k]*W2[h,k] + S*T*b2[h] ) / B
// GEMM1 in split-bf16 MFMA (Ahi*Whi + Ahi*Wlo + Alo*Whi), rows permuted to
// r' = b*64 + s so each BM=64 block owns one batch element's full sequence
// and runs the LIF recurrence in-block (h1 never touches HBM).
//
// ws: part[4MB) | cnt[256KB) | Ahi(8M) Alo(8M) Whi(2M) Wlo(2M)

#define TSTEPS 10
#define SEQ    64
#define BATCH  64
#define EDIM   1024
#define HDIM   1024
#define NROW   (SEQ * BATCH)   // 4096
#define KSPLIT 16

typedef unsigned short u16;
typedef __attribute__((ext_vector_type(8))) short  short8;
typedef __attribute__((ext_vector_type(8))) unsigned short ushort8;
typedef __attribute__((ext_vector_type(4))) float  f32x4;

__device__ __forceinline__ u16 rne_bf16(float x) {
    unsigned u = __float_as_uint(x);
    u += 0x7fffu + ((u >> 16) & 1u);
    return (u16)(u >> 16);
}
__device__ __forceinline__ float bf16f(u16 h) {
    return __uint_as_float(((unsigned)h) << 16);
}
__device__ __forceinline__ void gld16(const u16* g, u16* l) {
    __builtin_amdgcn_global_load_lds(
        (const __attribute__((address_space(1))) void*)g,
        (__attribute__((address_space(3))) void*)l, 16, 0, 0);
}

// ---- split fp32 -> bf16 hi/lo. rows [0,4096): emb gather, permuted so that
// ---- dst row r' = b*64+s pulls idx[s*64+b]; rows [4096,5120): W1.
__global__ __launch_bounds__(256) void split_pack(
    const float* __restrict__ emb, const float* __restrict__ W1,
    const int* __restrict__ idx,
    u16* __restrict__ ahi, u16* __restrict__ alo,
    u16* __restrict__ whi, u16* __restrict__ wlo)
{
    const int t = blockIdx.x * 256 + threadIdx.x;
    const int r = t >> 7;
    const int c = (t & 127) << 3;
    const float* src;
    u16 *dh, *dl;
    if (r < NROW) {
        const int srow = idx[(r & 63) * 64 + (r >> 6)];   // r = b*64+s -> idx[s*64+b]
        src = emb + (size_t)srow * EDIM + c;
        dh = ahi + (size_t)r * EDIM + c;
        dl = alo + (size_t)r * EDIM + c;
    } else {
        const int rw = r - NROW;
        src = W1 + (size_t)rw * EDIM + c;
        dh = whi + (size_t)rw * EDIM + c;
        dl = wlo + (size_t)rw * EDIM + c;
    }
    float4 v0 = *(const float4*)src;
    float4 v1 = *(const float4*)(src + 4);
    float x[8] = {v0.x, v0.y, v0.z, v0.w, v1.x, v1.y, v1.z, v1.w};
    ushort8 h, l;
#pragma unroll
    for (int j = 0; j < 8; ++j) {
        u16 hh = rne_bf16(x[j]);
        h[j] = hh;
        l[j] = rne_bf16(x[j] - bf16f(hh));
    }
    *(ushort8*)dh = h;
    *(ushort8*)dl = l;
}

// ---- GEMM1(split-bf16 MFMA) + in-block LIF spike count -------------------
#define BM 64
#define BN 128
#define BK 32
#define NT (EDIM / BK)
// u16 offsets inside one 24KB buffer:
#define AH 0          // [64][32]
#define AL 2048
#define WH 4096       // [128][32]
#define WL 8192
#define BUF 12288     // 24KB

__global__ __launch_bounds__(256) void gemm1_lif(
    const u16* __restrict__ Ahi, const u16* __restrict__ Alo,
    const u16* __restrict__ Whi, const u16* __restrict__ Wlo,
    const float* __restrict__ bias1,
    const float* __restrict__ pthr, const float* __restrict__ pleak,
    float* __restrict__ cnt)
{
    __shared__ unsigned char smraw[2 * BUF * 2];   // 48KB: staging / ct alias
    u16*   stage = (u16*)smraw;
    float* ct    = (float*)smraw;                  // [128][65] fp32 (33.3KB)

    // bijective XCD-chunk swizzle: 512 blocks, chunk = 8 by x 8 bx per XCD
    const int bid = blockIdx.x;
    const int loc = bid >> 3;
    const int by  = (bid & 7) * 8 + (loc & 7);     // 0..63  (= batch b)
    const int bx  = loc >> 3;                      // 0..7   (k-slab)
    const int row0 = by * BM, col0 = bx * BN;

    const int tid  = threadIdx.x;
    const int wave = tid >> 6, lane = tid & 63;
    const int wn   = wave;                          // wave grid 1x4, tile 64x32
    const int lrow = lane & 15, kgrp = lane >> 4;

    // staging source: 16 rows per gld16, inverse slot-swizzled k-chunk
    const int srr = lane >> 2;                                // 0..15
    const int kcs = (((lane & 3) ^ ((lane >> 3) & 3)) << 3);  // u16 offset
    const size_t aoff = (size_t)(row0 + wave * 16 + srr) * EDIM + kcs;
    const size_t w0   = (size_t)(col0 + wave * 32 + srr) * EDIM + kcs;
    const size_t w1   = w0 + (size_t)16 * EDIM;

    f32x4 acc[4][2];
    const f32x4 zero = {0.f, 0.f, 0.f, 0.f};
#pragma unroll
    for (int m = 0; m < 4; ++m)
#pragma unroll
        for (int n = 0; n < 2; ++n) acc[m][n] = zero;

    auto STAGE = [&](int k0, int b) {
        u16* lb = stage + b * BUF;
        gld16(Ahi + aoff + k0, lb + AH + wave * 512);
        gld16(Alo + aoff + k0, lb + AL + wave * 512);
        gld16(Whi + w0 + k0, lb + WH + wave * 1024);
        gld16(Whi + w1 + k0, lb + WH + wave * 1024 + 512);
        gld16(Wlo + w0 + k0, lb + WL + wave * 1024);
        gld16(Wlo + w1 + k0, lb + WL + wave * 1024 + 512);
    };

    auto COMPUTE = [&](int b) {
        const u16* lb = stage + b * BUF;
        short8 ah[4], al[4], bh[2], bl[2];
#pragma unroll
        for (int n = 0; n < 2; ++n) {
            const int c = wn * 32 + n * 16 + lrow;
            const int s = kgrp ^ ((c >> 1) & 3);
            const u16* p = lb + WH + c * 32 + s * 8;
            bh[n] = *(const short8*)p;
            bl[n] = *(const short8*)(p + (WL - WH));
        }
#pragma unroll
        for (int m = 0; m < 4; ++m) {
            const int r = m * 16 + lrow;
            const int s = kgrp ^ ((r >> 1) & 3);
            const u16* p = lb + AH + r * 32 + s * 8;
            ah[m] = *(const short8*)p;
            al[m] = *(const short8*)(p + (AL - AH));
        }
#pragma unroll
        for (int m = 0; m < 4; ++m)
#pragma unroll
            for (int n = 0; n < 2; ++n) {
                acc[m][n] = __builtin_amdgcn_mfma_f32_16x16x32_bf16(ah[m], bh[n], acc[m][n], 0, 0, 0);
                acc[m][n] = __builtin_amdgcn_mfma_f32_16x16x32_bf16(ah[m], bl[n], acc[m][n], 0, 0, 0);
                acc[m][n] = __builtin_amdgcn_mfma_f32_16x16x32_bf16(al[m], bh[n], acc[m][n], 0, 0, 0);
            }
    };

    STAGE(0, 0);
    __syncthreads();
    int cur = 0;
#pragma unroll 2
    for (int kt = 0; kt < NT; ++kt) {
        if (kt + 1 < NT) STAGE((kt + 1) * BK, cur ^ 1);
        COMPUTE(cur);
        __syncthreads();
        cur ^= 1;
    }
    // last barrier done: all MFMA LDS reads complete -> safe to alias with ct

    // C/D layout: col=lane&15, row=(lane>>4)*4+j.  ct[kcol][s], stride 65.
#pragma unroll
    for (int n = 0; n < 2; ++n) {
        const int kc = wn * 32 + n * 16 + lrow;
#pragma unroll
        for (int m = 0; m < 4; ++m) {
            const int sb = m * 16 + kgrp * 4;
#pragma unroll
            for (int j = 0; j < 4; ++j)
                ct[kc * 65 + sb + j] = acc[m][n][j];
        }
    }
    __syncthreads();

    // LIF recurrence: thread k walks ct[k][s], s=0..63, 10 substeps each
    if (tid < BN) {
        const float thr = pthr[0];
        const float lk  = pleak[0];
        const float b1v = bias1[col0 + tid];
        const float* row = ct + tid * 65;
        float mem1 = 0.f, c = 0.f;
        for (int s = 0; s < SEQ; ++s) {
            const float x = row[s] + b1v;
#pragma unroll
            for (int t = 0; t < TSTEPS; ++t) {
                mem1 = lk * mem1 + x;
                if (mem1 > thr) { c += 1.f; mem1 -= thr; }
            }
        }
        cnt[(size_t)by * HDIM + col0 + tid] = c;
    }
}

// ---- GEMM2 (K-split partials): part[kc][b][h] ----------------------------
__global__ __launch_bounds__(256) void gemm2_partial(
    const float* __restrict__ cnt,
    const float* __restrict__ W2,
    float* __restrict__ part)
{
    __shared__ float As[32][68];
    __shared__ float Bs[32][132];

    const int tid   = threadIdx.x;
    const int col0  = blockIdx.x * 128;
    const int kc    = blockIdx.y;
    const int kbase = kc * 64;

    const int lr = tid >> 3;
    const int lc = (tid & 7) * 4;
    const int tm = (tid >> 4) * 4;
    const int tn = (tid & 15) * 4;

    float acc[4][8];
#pragma unroll
    for (int i = 0; i < 4; ++i)
#pragma unroll
        for (int j = 0; j < 8; ++j) acc[i][j] = 0.f;

    for (int kt = 0; kt < 2; ++kt) {
        const int k0 = kbase + kt * 32;
#pragma unroll
        for (int p = 0; p < 2; ++p) {
            int r = p * 32 + lr;
            float4 v = *(const float4*)(cnt + (size_t)r * HDIM + k0 + lc);
            As[lc + 0][r] = v.x; As[lc + 1][r] = v.y;
            As[lc + 2][r] = v.z; As[lc + 3][r] = v.w;
        }
#pragma unroll
        for (int p = 0; p < 4; ++p) {
            int r = p * 32 + lr;
            float4 v = *(const float4*)(W2 + (size_t)(col0 + r) * HDIM + k0 + lc);
            Bs[lc + 0][r] = v.x; Bs[lc + 1][r] = v.y;
            Bs[lc + 2][r] = v.z; Bs[lc + 3][r] = v.w;
        }
        __syncthreads();
#pragma unroll 8
        for (int k = 0; k < 32; ++k) {
            float4 a   = *(const float4*)&As[k][tm];
            float4 bb0 = *(const float4*)&Bs[k][tn];
            float4 bb1 = *(const float4*)&Bs[k][tn + 64];
            float av[4] = {a.x, a.y, a.z, a.w};
            float bv[8] = {bb0.x, bb0.y, bb0.z, bb0.w, bb1.x, bb1.y, bb1.z, bb1.w};
#pragma unroll
            for (int i = 0; i < 4; ++i)
#pragma unroll
                for (int j = 0; j < 8; ++j)
                    acc[i][j] += av[i] * bv[j];
        }
        __syncthreads();
    }

#pragma unroll
    for (int i = 0; i < 4; ++i) {
        float* prow = part + (size_t)kc * (BATCH * HDIM) + (size_t)(tm + i) * HDIM + col0;
        float4 o0, o1;
        o0.x = acc[i][0]; o0.y = acc[i][1]; o0.z = acc[i][2]; o0.w = acc[i][3];
        o1.x = acc[i][4]; o1.y = acc[i][5]; o1.z = acc[i][6]; o1.w = acc[i][7];
        *(float4*)(prow + tn)      = o0;
        *(float4*)(prow + tn + 64) = o1;
    }
}

// ---- final reduce: out = (sum_kc part + 640*b2) / 64 ----------------------
__global__ __launch_bounds__(256) void reduce_out(
    const float* __restrict__ part,
    const float* __restrict__ b2,
    float* __restrict__ out)
{
    const int i = blockIdx.x * 256 + threadIdx.x;
    float s = 0.f;
#pragma unroll
    for (int kc = 0; kc < KSPLIT; ++kc)
        s += part[(size_t)kc * (BATCH * HDIM) + i];
    const int h = i & (HDIM - 1);
    out[i] = (s + (float)(SEQ * TSTEPS) * b2[h]) * (1.0f / (float)BATCH);
}

extern "C" void kernel_launch(void* const* d_in, const int* in_sizes, int n_in,
                              void* d_out, int out_size, void* d_ws, size_t ws_size,
                              hipStream_t stream)
{
    (void)in_sizes; (void)n_in; (void)out_size; (void)ws_size;

    const int*   idx  = (const int*)d_in[0];
    const float* emb  = (const float*)d_in[1];
    const float* W1   = (const float*)d_in[2];
    const float* b1   = (const float*)d_in[3];
    const float* W2   = (const float*)d_in[4];
    const float* b2   = (const float*)d_in[5];
    const float* thr  = (const float*)d_in[6];
    const float* leak = (const float*)d_in[7];
    float* out = (float*)d_out;

    char* ws = (char*)d_ws;
    float* part = (float*)ws;                                       // 4 MB
    float* cnt  = (float*)(ws + (size_t)KSPLIT * BATCH * HDIM * 4); // 256 KB
    u16* ahi = (u16*)(ws + (size_t)KSPLIT * BATCH * HDIM * 4 + (size_t)BATCH * HDIM * 4);
    u16* alo = ahi + (size_t)NROW * EDIM;
    u16* whi = alo + (size_t)NROW * EDIM;
    u16* wlo = whi + (size_t)HDIM * EDIM;

    split_pack<<<dim3((NROW + HDIM) * 128 / 256), 256, 0, stream>>>(
        emb, W1, idx, ahi, alo, whi, wlo);

    gemm1_lif<<<dim3((NROW / BM) * (HDIM / BN)), 256, 0, stream>>>(
        ahi, alo, whi, wlo, b1, thr, leak, cnt);

    gemm2_partial<<<dim3(HDIM / 128, KSPLIT), 256, 0, stream>>>(cnt, W2, part);

    reduce_out<<<dim3((BATCH * HDIM) / 256), 256, 0, stream>>>(part, b2, out);
}

// Round 4
// 56.802 us; speedup vs baseline: 2.8541x; 1.1387x over previous
//
#include <hip/hip_runtime.h>

// SpikeEncoder: out[b,h] = ( sum_k count[b,k]*W2[h,k] + S*T*b2[h] ) / B
// GEMM1 in split-fp16 MFMA, 2 terms: A*W ~= Ahi*Whi + 2^-11*(Alo')*Whi,
// Alo' = (A - Ahi)*2^11 (kept in fp16 normal range; separate f32 accum).
// Rows permuted to r' = b*64 + s so each BM=64 block owns one batch
// element's full sequence and runs the LIF recurrence in-block.
//
// ws: part[4MB) | cnt[256KB) | Ahi(8M) Alo(8M) Whi(2M)

#define TSTEPS 10
#define SEQ    64
#define BATCH  64
#define EDIM   1024
#define HDIM   1024
#define NROW   (SEQ * BATCH)   // 4096
#define KSPLIT 16

typedef unsigned short u16;
typedef __attribute__((ext_vector_type(8))) _Float16 half8;
typedef __attribute__((ext_vector_type(8))) unsigned short ushort8;
typedef __attribute__((ext_vector_type(4))) float  f32x4;

union h16 { _Float16 f; u16 u; };

__device__ __forceinline__ u16 f2h_bits(float x) {
    h16 t; t.f = (_Float16)x; return t.u;       // RNE
}
__device__ __forceinline__ float h2f(u16 b) {
    h16 t; t.u = b; return (float)t.f;
}
__device__ __forceinline__ void gld16(const u16* g, u16* l) {
    __builtin_amdgcn_global_load_lds(
        (const __attribute__((address_space(1))) void*)g,
        (__attribute__((address_space(3))) void*)l, 16, 0, 0);
}

// ---- split fp32 -> fp16 hi + scaled-lo. rows [0,4096): emb gather with the
// ---- b*64+s permutation; rows [4096,5120): W1 (hi only).
__global__ __launch_bounds__(256) void split_pack(
    const float* __restrict__ emb, const float* __restrict__ W1,
    const int* __restrict__ idx,
    u16* __restrict__ ahi, u16* __restrict__ alo, u16* __restrict__ whi)
{
    const int t = blockIdx.x * 256 + threadIdx.x;
    const int r = t >> 7;
    const int c = (t & 127) << 3;
    if (r < NROW) {
        const int srow = idx[(r & 63) * 64 + (r >> 6)];   // r = b*64+s
        const float* src = emb + (size_t)srow * EDIM + c;
        float4 v0 = *(const float4*)src;
        float4 v1 = *(const float4*)(src + 4);
        float x[8] = {v0.x, v0.y, v0.z, v0.w, v1.x, v1.y, v1.z, v1.w};
        ushort8 h, l;
#pragma unroll
        for (int j = 0; j < 8; ++j) {
            u16 hh = f2h_bits(x[j]);
            h[j] = hh;
            l[j] = f2h_bits((x[j] - h2f(hh)) * 2048.0f);
        }
        *(ushort8*)(ahi + (size_t)r * EDIM + c) = h;
        *(ushort8*)(alo + (size_t)r * EDIM + c) = l;
    } else {
        const int rw = r - NROW;
        const float* src = W1 + (size_t)rw * EDIM + c;
        float4 v0 = *(const float4*)src;
        float4 v1 = *(const float4*)(src + 4);
        float x[8] = {v0.x, v0.y, v0.z, v0.w, v1.x, v1.y, v1.z, v1.w};
        ushort8 h;
#pragma unroll
        for (int j = 0; j < 8; ++j) h[j] = f2h_bits(x[j]);
        *(ushort8*)(whi + (size_t)rw * EDIM + c) = h;
    }
}

// ---- GEMM1(split-fp16 MFMA, 2-term) + in-block LIF spike count -----------
#define BM 64
#define BN 128
#define BK 32
#define NT (EDIM / BK)
// u16 offsets inside one 16KB buffer:
#define AH 0          // [64][32]
#define AL 2048
#define WH 4096       // [128][32]
#define BUF 8192      // 16KB

__global__ __launch_bounds__(256) void gemm1_lif(
    const u16* __restrict__ Ahi, const u16* __restrict__ Alo,
    const u16* __restrict__ Whi,
    const float* __restrict__ bias1,
    const float* __restrict__ pthr, const float* __restrict__ pleak,
    float* __restrict__ cnt)
{
    __shared__ float smf[8448];                 // 33792B: staging / ct alias
    u16*   stage = (u16*)smf;                   // 2 x 16KB double buffer
    float* ct    = smf;                         // [128][66] fp32

    // bijective XCD-chunk swizzle: 512 blocks, 8 by x 8 bx chunk per XCD
    const int bid = blockIdx.x;
    const int loc = bid >> 3;
    const int by  = (bid & 7) * 8 + (loc & 7);  // 0..63  (= batch b)
    const int bx  = loc >> 3;                   // 0..7   (k-slab)
    const int row0 = by * BM, col0 = bx * BN;

    const int tid  = threadIdx.x;
    const int wave = tid >> 6, lane = tid & 63;
    const int wn   = wave;                      // wave grid 1x4, tile 64x32
    const int lrow = lane & 15, kgrp = lane >> 4;

    // staging source: 16 rows per gld16, inverse slot-swizzled k-chunk
    const int srr = lane >> 2;                                // 0..15
    const int kcs = (((lane & 3) ^ ((lane >> 3) & 3)) << 3);  // u16 offset
    const size_t aoff = (size_t)(row0 + wave * 16 + srr) * EDIM + kcs;
    const size_t w0   = (size_t)(col0 + wave * 32 + srr) * EDIM + kcs;
    const size_t w1   = w0 + (size_t)16 * EDIM;

    f32x4 acc[4][2], acl[4][2];
    const f32x4 zero = {0.f, 0.f, 0.f, 0.f};
#pragma unroll
    for (int m = 0; m < 4; ++m)
#pragma unroll
        for (int n = 0; n < 2; ++n) { acc[m][n] = zero; acl[m][n] = zero; }

    auto STAGE = [&](int k0, int b) {
        u16* lb = stage + b * BUF;
        gld16(Ahi + aoff + k0, lb + AH + wave * 512);
        gld16(Alo + aoff + k0, lb + AL + wave * 512);
        gld16(Whi + w0 + k0, lb + WH + wave * 1024);
        gld16(Whi + w1 + k0, lb + WH + wave * 1024 + 512);
    };

    auto COMPUTE = [&](int b) {
        const u16* lb = stage + b * BUF;
        half8 ah[4], al[4], bh[2];
#pragma unroll
        for (int n = 0; n < 2; ++n) {
            const int c = wn * 32 + n * 16 + lrow;
            const int s = kgrp ^ ((c >> 1) & 3);
            bh[n] = *(const half8*)(lb + WH + c * 32 + s * 8);
        }
#pragma unroll
        for (int m = 0; m < 4; ++m) {
            const int r = m * 16 + lrow;
            const int s = kgrp ^ ((r >> 1) & 3);
            const u16* p = lb + AH + r * 32 + s * 8;
            ah[m] = *(const half8*)p;
            al[m] = *(const half8*)(p + (AL - AH));
        }
#pragma unroll
        for (int m = 0; m < 4; ++m)
#pragma unroll
            for (int n = 0; n < 2; ++n) {
                acc[m][n] = __builtin_amdgcn_mfma_f32_16x16x32_f16(ah[m], bh[n], acc[m][n], 0, 0, 0);
                acl[m][n] = __builtin_amdgcn_mfma_f32_16x16x32_f16(al[m], bh[n], acl[m][n], 0, 0, 0);
            }
    };

    STAGE(0, 0);
    __syncthreads();
    int cur = 0;
#pragma unroll 2
    for (int kt = 0; kt < NT; ++kt) {
        if (kt + 1 < NT) STAGE((kt + 1) * BK, cur ^ 1);
        COMPUTE(cur);
        __syncthreads();
        cur ^= 1;
    }
    // all MFMA LDS reads complete -> safe to alias staging with ct

    // C/D layout: col=lane&15, row=(lane>>4)*4+j.  ct[kcol][s], stride 66.
#pragma unroll
    for (int n = 0; n < 2; ++n) {
        const int kc = wn * 32 + n * 16 + lrow;
#pragma unroll
        for (int m = 0; m < 4; ++m) {
            const int sb = m * 16 + kgrp * 4;
#pragma unroll
            for (int j = 0; j < 4; ++j)
                ct[kc * 66 + sb + j] = acc[m][n][j] + acl[m][n][j] * (1.0f / 2048.0f);
        }
    }
    __syncthreads();

    // LIF recurrence: thread k walks ct[k][s], s=0..63, 10 substeps each
    if (tid < BN) {
        const float thr = pthr[0];
        const float lk  = pleak[0];
        const float b1v = bias1[col0 + tid];
        const float* row = ct + tid * 66;
        float mem1 = 0.f, c = 0.f;
        for (int s = 0; s < SEQ; ++s) {
            const float x = row[s] + b1v;
#pragma unroll
            for (int t = 0; t < TSTEPS; ++t) {
                mem1 = lk * mem1 + x;
                if (mem1 > thr) { c += 1.f; mem1 -= thr; }
            }
        }
        cnt[(size_t)by * HDIM + col0 + tid] = c;
    }
}

// ---- GEMM2 (K-split partials): part[kc][b][h] ----------------------------
__global__ __launch_bounds__(256) void gemm2_partial(
    const float* __restrict__ cnt,
    const float* __restrict__ W2,
    float* __restrict__ part)
{
    __shared__ float As[32][68];
    __shared__ float Bs[32][132];

    const int tid   = threadIdx.x;
    const int col0  = blockIdx.x * 128;
    const int kc    = blockIdx.y;
    const int kbase = kc * 64;

    const int lr = tid >> 3;
    const int lc = (tid & 7) * 4;
    const int tm = (tid >> 4) * 4;
    const int tn = (tid & 15) * 4;

    float acc[4][8];
#pragma unroll
    for (int i = 0; i < 4; ++i)
#pragma unroll
        for (int j = 0; j < 8; ++j) acc[i][j] = 0.f;

    for (int kt = 0; kt < 2; ++kt) {
        const int k0 = kbase + kt * 32;
#pragma unroll
        for (int p = 0; p < 2; ++p) {
            int r = p * 32 + lr;
            float4 v = *(const float4*)(cnt + (size_t)r * HDIM + k0 + lc);
            As[lc + 0][r] = v.x; As[lc + 1][r] = v.y;
            As[lc + 2][r] = v.z; As[lc + 3][r] = v.w;
        }
#pragma unroll
        for (int p = 0; p < 4; ++p) {
            int r = p * 32 + lr;
            float4 v = *(const float4*)(W2 + (size_t)(col0 + r) * HDIM + k0 + lc);
            Bs[lc + 0][r] = v.x; Bs[lc + 1][r] = v.y;
            Bs[lc + 2][r] = v.z; Bs[lc + 3][r] = v.w;
        }
        __syncthreads();
#pragma unroll 8
        for (int k = 0; k < 32; ++k) {
            float4 a   = *(const float4*)&As[k][tm];
            float4 bb0 = *(const float4*)&Bs[k][tn];
            float4 bb1 = *(const float4*)&Bs[k][tn + 64];
            float av[4] = {a.x, a.y, a.z, a.w};
            float bv[8] = {bb0.x, bb0.y, bb0.z, bb0.w, bb1.x, bb1.y, bb1.z, bb1.w};
#pragma unroll
            for (int i = 0; i < 4; ++i)
#pragma unroll
                for (int j = 0; j < 8; ++j)
                    acc[i][j] += av[i] * bv[j];
        }
        __syncthreads();
    }

#pragma unroll
    for (int i = 0; i < 4; ++i) {
        float* prow = part + (size_t)kc * (BATCH * HDIM) + (size_t)(tm + i) * HDIM + col0;
        float4 o0, o1;
        o0.x = acc[i][0]; o0.y = acc[i][1]; o0.z = acc[i][2]; o0.w = acc[i][3];
        o1.x = acc[i][4]; o1.y = acc[i][5]; o1.z = acc[i][6]; o1.w = acc[i][7];
        *(float4*)(prow + tn)      = o0;
        *(float4*)(prow + tn + 64) = o1;
    }
}

// ---- final reduce: out = (sum_kc part + 640*b2) / 64 ----------------------
__global__ __launch_bounds__(256) void reduce_out(
    const float* __restrict__ part,
    const float* __restrict__ b2,
    float* __restrict__ out)
{
    const int i = blockIdx.x * 256 + threadIdx.x;
    float s = 0.f;
#pragma unroll
    for (int kc = 0; kc < KSPLIT; ++kc)
        s += part[(size_t)kc * (BATCH * HDIM) + i];
    const int h = i & (HDIM - 1);
    out[i] = (s + (float)(SEQ * TSTEPS) * b2[h]) * (1.0f / (float)BATCH);
}

extern "C" void kernel_launch(void* const* d_in, const int* in_sizes, int n_in,
                              void* d_out, int out_size, void* d_ws, size_t ws_size,
                              hipStream_t stream)
{
    (void)in_sizes; (void)n_in; (void)out_size; (void)ws_size;

    const int*   idx  = (const int*)d_in[0];
    const float* emb  = (const float*)d_in[1];
    const float* W1   = (const float*)d_in[2];
    const float* b1   = (const float*)d_in[3];
    const float* W2   = (const float*)d_in[4];
    const float* b2   = (const float*)d_in[5];
    const float* thr  = (const float*)d_in[6];
    const float* leak = (const float*)d_in[7];
    float* out = (float*)d_out;

    char* ws = (char*)d_ws;
    float* part = (float*)ws;                                       // 4 MB
    float* cnt  = (float*)(ws + (size_t)KSPLIT * BATCH * HDIM * 4); // 256 KB
    u16* ahi = (u16*)(ws + (size_t)KSPLIT * BATCH * HDIM * 4 + (size_t)BATCH * HDIM * 4);
    u16* alo = ahi + (size_t)NROW * EDIM;
    u16* whi = alo + (size_t)NROW * EDIM;

    split_pack<<<dim3((NROW + HDIM) * 128 / 256), 256, 0, stream>>>(
        emb, W1, idx, ahi, alo, whi);

    gemm1_lif<<<dim3((NROW / BM) * (HDIM / BN)), 256, 0, stream>>>(
        ahi, alo, whi, b1, thr, leak, cnt);

    gemm2_partial<<<dim3(HDIM / 128, KSPLIT), 256, 0, stream>>>(cnt, W2, part);

    reduce_out<<<dim3((BATCH * HDIM) / 256), 256, 0, stream>>>(part, b2, out);
}